// Round 1
// baseline (348.437 us; speedup 1.0000x reference)
//
#include <hip/hip_runtime.h>
#include <math.h>

#define Bn 8
#define Nn 2048
#define FIn 256
#define FOn 128

typedef __attribute__((ext_vector_type(8))) short short8;
typedef __attribute__((ext_vector_type(4))) float f32x4;
typedef __attribute__((ext_vector_type(4))) unsigned short ushort4v;

__device__ __forceinline__ unsigned short f2bf(float x){
    union { float f; unsigned u; } v; v.f = x;
    unsigned r = v.u + 0x7fffu + ((v.u >> 16) & 1u);
    return (unsigned short)(r >> 16);
}

// K0: WT[o][k] = bf16(W[k][o])   (128 x 256)
__global__ void k0_wt(const float* __restrict__ W, unsigned short* __restrict__ WT){
    int o = blockIdx.x, k = threadIdx.x;
    WT[o*FIn + k] = f2bf(W[k*FOn + o]);
}

// K1: Wh = h @ W  (fp32 out), MFMA bf16. 64 rows/block, 4 waves, wave = 16 rows x 128 cols.
// A-frag: row = lane&15, k = (lane>>4)*8 + e  (loaded fp32 from global, cvt)
// B-frag: col = lane&15, k = (lane>>4)*8 + e  (ushort8 from WT, L2-resident)
__global__ __launch_bounds__(256) void k1_gemm(const float* __restrict__ h,
        const unsigned short* __restrict__ WT, float* __restrict__ Wh){
    int t = threadIdx.x, lane = t & 63, w = t >> 6;
    int l16 = lane & 15, khalf = (lane >> 4) * 8;
    long row = (long)blockIdx.x*64 + w*16 + l16;
    f32x4 acc[8];
    #pragma unroll
    for (int nf=0;nf<8;nf++) acc[nf] = (f32x4){0.f,0.f,0.f,0.f};
    #pragma unroll
    for (int ks=0; ks<8; ks++){
        int kb = ks*32 + khalf;
        const float4* hp = (const float4*)(h + row*FIn + kb);
        float4 h0 = hp[0], h1 = hp[1];
        short8 af;
        af[0]=(short)f2bf(h0.x); af[1]=(short)f2bf(h0.y); af[2]=(short)f2bf(h0.z); af[3]=(short)f2bf(h0.w);
        af[4]=(short)f2bf(h1.x); af[5]=(short)f2bf(h1.y); af[6]=(short)f2bf(h1.z); af[7]=(short)f2bf(h1.w);
        #pragma unroll
        for (int nf=0;nf<8;nf++){
            short8 bfv = *(const short8*)(WT + (nf*16 + l16)*FIn + kb);
            acc[nf] = __builtin_amdgcn_mfma_f32_16x16x32_bf16(af, bfv, acc[nf], 0, 0, 0);
        }
    }
    long orow = (long)blockIdx.x*64 + w*16 + ((lane>>4)<<2);
    #pragma unroll
    for (int nf=0;nf<8;nf++)
        #pragma unroll
        for (int r=0;r<4;r++)
            Wh[(orow + r)*FOn + nf*16 + l16] = acc[nf][r];
}

// K2: per 64-row tile: WhT[b][o][i] = bf16(Wh[i][o]); s1/s2 from fp32 Wh.
__global__ __launch_bounds__(256) void k2_sT(const float* __restrict__ Wh, const float* __restrict__ a,
        unsigned short* __restrict__ WhT, float* __restrict__ s1, float* __restrict__ s2){
    __shared__ __align__(16) float whf[64][132];
    int t = threadIdx.x;
    long g0 = (long)blockIdx.x * 64;
    int b = (int)(g0 >> 11);
    int i0 = (int)(g0 & 2047);
    #pragma unroll
    for (int it=0; it<8; it++){
        int c = it*256 + t;
        int r = c >> 5, c4 = (c & 31) * 4;
        *(float4*)&whf[r][c4] = *(const float4*)(Wh + (g0 + r)*FOn + c4);
    }
    __syncthreads();
    #pragma unroll
    for (int it=0; it<4; it++){
        int c = it*256 + t;
        int o = c >> 3, ic = (c & 7) * 8;
        short8 v;
        #pragma unroll
        for (int e=0;e<8;e++) v[e] = (short)f2bf(whf[ic+e][o]);
        *(short8*)(WhT + ((long)(b*FOn + o))*Nn + i0 + ic) = v;
    }
    if (t < 64){
        float u1=0.f, u2=0.f;
        for (int o=0;o<FOn;o++){
            float wv = whf[t][o];
            u1 = fmaf(wv, a[o], u1);
            u2 = fmaf(wv, a[FOn + o], u2);
        }
        s1[g0 + t] = u1;
        s2[g0 + t] = u2;
    }
}

// K3: fused masked-softmax-attention. Block = (b, 64-row i-tile), 4 waves.
// j-loop over 32 tiles of 64: scores on VALU (16-lane shfl reduce), online softmax,
// P(bf16)@WhT-tile via 16x16x32 MFMA. Epilogue: /l, elu, fp32 store.
__global__ __launch_bounds__(256) void k3_flash(const int* __restrict__ adj,
        const unsigned short* __restrict__ WhT, const float* __restrict__ s1g,
        const float* __restrict__ s2g, float* __restrict__ out){
    __shared__ __align__(16) unsigned short pt[64][72];
    __shared__ __align__(16) unsigned short vt[128][72];
    __shared__ float m_s[64], l_s[64], rs_s[64];
    int t = threadIdx.x, lane = t & 63, w = t >> 6;
    int bid = blockIdx.x;
    int b = bid >> 5;
    int i0 = (bid & 31) * 64;
    if (t < 64){ m_s[t] = -INFINITY; l_s[t] = 0.f; }
    f32x4 acc[8];
    #pragma unroll
    for (int nf=0;nf<8;nf++) acc[nf] = (f32x4){0.f,0.f,0.f,0.f};
    int q = t >> 4;           // 0..15: row-group within pass
    int c4 = (t & 15) * 4;    // 4 j-columns per thread
    float s1v[4];
    #pragma unroll
    for (int p=0;p<4;p++) s1v[p] = s1g[b*Nn + i0 + p*16 + q];
    __syncthreads();
    for (int jt=0; jt<32; jt++){
        int j0 = jt*64;
        // stage WhT tile: vt[col][jj], padded 72 to break bank conflicts
        #pragma unroll
        for (int it=0; it<4; it++){
            int c = it*256 + t;
            int colv = c >> 3, jc = (c & 7) * 8;
            *(short8*)&vt[colv][jc] = *(const short8*)(WhT + ((long)(b*FOn + colv))*Nn + j0 + jc);
        }
        // scores + online softmax (4 passes x 4 elems/thread)
        #pragma unroll
        for (int p=0;p<4;p++){
            int r = p*16 + q;
            int4 aj = *(const int4*)(adj + ((long)(b*Nn + i0 + r))*Nn + j0 + c4);
            float4 s2v = *(const float4*)(s2g + b*Nn + j0 + c4);
            float s1r = s1v[p];
            float sc0 = s1r + s2v.x; sc0 = sc0 > 0.f ? sc0 : 0.2f*sc0; sc0 = aj.x > 0 ? sc0 : -9e15f;
            float sc1 = s1r + s2v.y; sc1 = sc1 > 0.f ? sc1 : 0.2f*sc1; sc1 = aj.y > 0 ? sc1 : -9e15f;
            float sc2 = s1r + s2v.z; sc2 = sc2 > 0.f ? sc2 : 0.2f*sc2; sc2 = aj.z > 0 ? sc2 : -9e15f;
            float sc3 = s1r + s2v.w; sc3 = sc3 > 0.f ? sc3 : 0.2f*sc3; sc3 = aj.w > 0 ? sc3 : -9e15f;
            float tm = fmaxf(fmaxf(sc0, sc1), fmaxf(sc2, sc3));
            tm = fmaxf(tm, __shfl_xor(tm, 1));
            tm = fmaxf(tm, __shfl_xor(tm, 2));
            tm = fmaxf(tm, __shfl_xor(tm, 4));
            tm = fmaxf(tm, __shfl_xor(tm, 8));
            float mo = m_s[r];
            float mn = fmaxf(mo, tm);
            float rsc = __expf(mo - mn);      // 0 on first tile (mo=-inf)
            float p0 = __expf(sc0 - mn), p1 = __expf(sc1 - mn);
            float p2 = __expf(sc2 - mn), p3 = __expf(sc3 - mn);
            float ps = (p0+p1)+(p2+p3);
            ps += __shfl_xor(ps, 1); ps += __shfl_xor(ps, 2);
            ps += __shfl_xor(ps, 4); ps += __shfl_xor(ps, 8);
            if ((t & 15) == 0){ m_s[r] = mn; l_s[r] = l_s[r]*rsc + ps; rs_s[r] = rsc; }
            ushort4v pv;
            pv[0] = f2bf(p0); pv[1] = f2bf(p1); pv[2] = f2bf(p2); pv[3] = f2bf(p3);
            *(ushort4v*)&pt[r][c4] = pv;
        }
        __syncthreads();
        // rescale + MFMA (wave w: rows w*16..+15, all 128 cols)
        int r0 = w*16;
        #pragma unroll
        for (int reg=0;reg<4;reg++){
            float rv = rs_s[r0 + ((lane>>4)<<2) + reg];
            #pragma unroll
            for (int nf=0;nf<8;nf++) acc[nf][reg] *= rv;
        }
        int arow = r0 + (lane & 15);
        int khalf = (lane >> 4) * 8;
        #pragma unroll
        for (int kk=0;kk<2;kk++){
            short8 af = *(const short8*)&pt[arow][kk*32 + khalf];
            #pragma unroll
            for (int nf=0;nf<8;nf++){
                short8 bfv = *(const short8*)&vt[nf*16 + (lane & 15)][kk*32 + khalf];
                acc[nf] = __builtin_amdgcn_mfma_f32_16x16x32_bf16(af, bfv, acc[nf], 0, 0, 0);
            }
        }
        __syncthreads();
    }
    // epilogue: h' = acc / l, elu, store fp32
    int r0 = w*16;
    #pragma unroll
    for (int reg=0;reg<4;reg++){
        int r = r0 + ((lane>>4)<<2) + reg;
        float inv = 1.f / l_s[r];
        #pragma unroll
        for (int nf=0;nf<8;nf++){
            float v = acc[nf][reg] * inv;
            v = v > 0.f ? v : (__expf(v) - 1.f);
            out[((long)(b*Nn + i0 + r))*FOn + nf*16 + (lane & 15)] = v;
        }
    }
}

extern "C" void kernel_launch(void* const* d_in, const int* in_sizes, int n_in,
                              void* d_out, int out_size, void* d_ws, size_t ws_size,
                              hipStream_t stream){
    const float* h  = (const float*)d_in[0];
    const int* adj  = (const int*)d_in[1];
    const float* W  = (const float*)d_in[2];
    const float* a  = (const float*)d_in[3];
    float* out = (float*)d_out;
    char* ws = (char*)d_ws;
    // workspace layout (16B aligned):
    unsigned short* WT  = (unsigned short*)(ws);                       //   65,536 B (128x256 bf16)
    float* Wh           = (float*)(ws + 65536);                        // 8,388,608 B (16384x128 f32)
    unsigned short* WhT = (unsigned short*)(ws + 65536 + 8388608);     // 4,194,304 B (8x128x2048 bf16)
    float* s1           = (float*)(ws + 65536 + 8388608 + 4194304);    //   65,536 B
    float* s2           = (float*)(ws + 65536 + 8388608 + 4194304 + 65536);

    k0_wt  <<<128, 256, 0, stream>>>(W, WT);
    k1_gemm<<<256, 256, 0, stream>>>(h, WT, Wh);
    k2_sT  <<<256, 256, 0, stream>>>(Wh, a, WhT, s1, s2);
    k3_flash<<<256, 256, 0, stream>>>(adj, WhT, s1, s2, out);
}

// Round 2
// 237.293 us; speedup vs baseline: 1.4684x; 1.4684x over previous
//
#include <hip/hip_runtime.h>
#include <math.h>

#define Bn 8
#define Nn 2048
#define FIn 256
#define FOn 128

typedef __attribute__((ext_vector_type(8))) short short8;
typedef __attribute__((ext_vector_type(4))) float f32x4;
typedef __attribute__((ext_vector_type(4))) unsigned short ushort4v;

__device__ __forceinline__ unsigned short f2bf(float x){
    union { float f; unsigned u; } v; v.f = x;
    unsigned r = v.u + 0x7fffu + ((v.u >> 16) & 1u);
    return (unsigned short)(r >> 16);
}

// K0: WT[o][k] = bf16(W[k][o])   (128 x 256)
__global__ void k0_wt(const float* __restrict__ W, unsigned short* __restrict__ WT){
    int o = blockIdx.x, k = threadIdx.x;
    WT[o*FIn + k] = f2bf(W[k*FOn + o]);
}

// K1 (fused): Wh = h @ W via bf16 MFMA; writes WhT (bf16 transposed) + s1/s2 in-register.
// 64 rows/block, 4 waves, wave = 16 rows x 128 cols.
__global__ __launch_bounds__(256) void k1_gemm(const float* __restrict__ h,
        const unsigned short* __restrict__ WT, const float* __restrict__ a,
        unsigned short* __restrict__ WhT, float* __restrict__ s1, float* __restrict__ s2){
    __shared__ __align__(16) unsigned short tr[128][72];
    int t = threadIdx.x, lane = t & 63, w = t >> 6;
    int l16 = lane & 15, khalf = (lane >> 4) * 8;
    long g0 = (long)blockIdx.x * 64;
    int b = (int)(g0 >> 11);
    int i0 = (int)(g0 & 2047);
    long row = g0 + w*16 + l16;
    f32x4 acc[8];
    #pragma unroll
    for (int nf=0;nf<8;nf++) acc[nf] = (f32x4){0.f,0.f,0.f,0.f};
    #pragma unroll
    for (int ks=0; ks<8; ks++){
        int kb = ks*32 + khalf;
        const float4* hp = (const float4*)(h + row*FIn + kb);
        float4 h0 = hp[0], h1 = hp[1];
        short8 af;
        af[0]=(short)f2bf(h0.x); af[1]=(short)f2bf(h0.y); af[2]=(short)f2bf(h0.z); af[3]=(short)f2bf(h0.w);
        af[4]=(short)f2bf(h1.x); af[5]=(short)f2bf(h1.y); af[6]=(short)f2bf(h1.z); af[7]=(short)f2bf(h1.w);
        #pragma unroll
        for (int nf=0;nf<8;nf++){
            short8 bfv = *(const short8*)(WT + (nf*16 + l16)*FIn + kb);
            acc[nf] = __builtin_amdgcn_mfma_f32_16x16x32_bf16(af, bfv, acc[nf], 0, 0, 0);
        }
    }
    // s1/s2 in-register: reduce over the 16 col-lanes (l16) of each lane-group
    {
        float a1v[8], a2v[8];
        #pragma unroll
        for (int nf=0;nf<8;nf++){ a1v[nf] = a[nf*16 + l16]; a2v[nf] = a[FOn + nf*16 + l16]; }
        #pragma unroll
        for (int r=0;r<4;r++){
            float u1 = 0.f, u2 = 0.f;
            #pragma unroll
            for (int nf=0;nf<8;nf++){ u1 = fmaf(acc[nf][r], a1v[nf], u1); u2 = fmaf(acc[nf][r], a2v[nf], u2); }
            u1 += __shfl_xor(u1, 1); u1 += __shfl_xor(u1, 2); u1 += __shfl_xor(u1, 4); u1 += __shfl_xor(u1, 8);
            u2 += __shfl_xor(u2, 1); u2 += __shfl_xor(u2, 2); u2 += __shfl_xor(u2, 4); u2 += __shfl_xor(u2, 8);
            if (l16 == 0){
                long rw = g0 + w*16 + ((lane>>4)<<2) + r;
                s1[rw] = u1; s2[rw] = u2;
            }
        }
    }
    // WhT via LDS transpose (bf16), coalesced write-out
    int rbase = w*16 + ((lane>>4)<<2);
    #pragma unroll
    for (int nf=0;nf<8;nf++)
        #pragma unroll
        for (int r=0;r<4;r++)
            tr[nf*16 + l16][rbase + r] = f2bf(acc[nf][r]);
    __syncthreads();
    int o = t >> 1, seg = t & 1;
    #pragma unroll
    for (int e=0;e<4;e++){
        short8 v = *(const short8*)&tr[o][seg*32 + e*8];
        *(short8*)(WhT + ((long)(b*FOn + o))*Nn + i0 + seg*32 + e*8) = v;
    }
}

// K3: fused masked-softmax-attention. Block = (b, 64-row i-tile), 512 threads = 8 waves.
// Half hf = w>>2 handles j in [hf*1024, hf*1024+1024) (16 tiles of 64) with its own
// online softmax state; register prefetch of adj/s2/WhT-stage one tile ahead; merge
// the two halves' (m,l,acc) through LDS at the end.
__global__ __launch_bounds__(512) void k3_flash(const int* __restrict__ adj,
        const unsigned short* __restrict__ WhT, const float* __restrict__ s1g,
        const float* __restrict__ s2g, float* __restrict__ out){
    __shared__ __align__(16) unsigned short pt[2][64][72];
    __shared__ __align__(16) unsigned short vt[2][128][72];   // reused as fp32 merge buffer (32KB <= 36.8KB)
    __shared__ float m_s[2][64], l_s[2][64], rs_s[2][64];
    int t = threadIdx.x, lane = t & 63, w = t >> 6;
    int hf = w >> 2, wl = w & 3, th = t & 255;
    int bid = blockIdx.x;
    int b = bid >> 5;
    int i0 = (bid & 31) * 64;
    int q = th >> 4;           // 0..15: row-group within pass
    int c4 = (th & 15) * 4;    // 4 j-columns per thread
    if (th < 64){ m_s[hf][th] = -INFINITY; l_s[hf][th] = 0.f; }
    f32x4 acc[8];
    #pragma unroll
    for (int nf=0;nf<8;nf++) acc[nf] = (f32x4){0.f,0.f,0.f,0.f};
    float s1v[4];
    #pragma unroll
    for (int p=0;p<4;p++) s1v[p] = s1g[b*Nn + i0 + p*16 + q];
    int jbase = hf * 1024;
    int4 ajp[4]; float4 s2p; short8 vtp[4];
    {   // prefetch tile 0
        int j0 = jbase;
        #pragma unroll
        for (int p=0;p<4;p++) ajp[p] = *(const int4*)(adj + ((long)(b*Nn + i0 + p*16 + q))*Nn + j0 + c4);
        s2p = *(const float4*)(s2g + b*Nn + j0 + c4);
        #pragma unroll
        for (int it=0; it<4; it++){
            int c = it*256 + th;
            vtp[it] = *(const short8*)(WhT + ((long)(b*FOn + (c>>3)))*Nn + j0 + (c&7)*8);
        }
    }
    for (int jt=0; jt<16; jt++){
        int4 ajc[4];
        #pragma unroll
        for (int p=0;p<4;p++) ajc[p] = ajp[p];
        float4 s2c = s2p;
        __syncthreads();   // previous iter's MFMA done reading pt/vt
        #pragma unroll
        for (int it=0; it<4; it++){
            int c = it*256 + th;
            *(short8*)&vt[hf][c>>3][(c&7)*8] = vtp[it];
        }
        if (jt < 15){   // prefetch next tile (hides HBM latency under scores+MFMA)
            int j0 = jbase + (jt+1)*64;
            #pragma unroll
            for (int p=0;p<4;p++) ajp[p] = *(const int4*)(adj + ((long)(b*Nn + i0 + p*16 + q))*Nn + j0 + c4);
            s2p = *(const float4*)(s2g + b*Nn + j0 + c4);
            #pragma unroll
            for (int it=0; it<4; it++){
                int c = it*256 + th;
                vtp[it] = *(const short8*)(WhT + ((long)(b*FOn + (c>>3)))*Nn + j0 + (c&7)*8);
            }
        }
        // scores + online softmax (4 passes x 4 elems/thread)
        #pragma unroll
        for (int p=0;p<4;p++){
            int r = p*16 + q;
            float s1r = s1v[p];
            float sc0 = s1r + s2c.x; sc0 = sc0 > 0.f ? sc0 : 0.2f*sc0; sc0 = ajc[p].x > 0 ? sc0 : -9e15f;
            float sc1 = s1r + s2c.y; sc1 = sc1 > 0.f ? sc1 : 0.2f*sc1; sc1 = ajc[p].y > 0 ? sc1 : -9e15f;
            float sc2 = s1r + s2c.z; sc2 = sc2 > 0.f ? sc2 : 0.2f*sc2; sc2 = ajc[p].z > 0 ? sc2 : -9e15f;
            float sc3 = s1r + s2c.w; sc3 = sc3 > 0.f ? sc3 : 0.2f*sc3; sc3 = ajc[p].w > 0 ? sc3 : -9e15f;
            float tm = fmaxf(fmaxf(sc0, sc1), fmaxf(sc2, sc3));
            tm = fmaxf(tm, __shfl_xor(tm, 1));
            tm = fmaxf(tm, __shfl_xor(tm, 2));
            tm = fmaxf(tm, __shfl_xor(tm, 4));
            tm = fmaxf(tm, __shfl_xor(tm, 8));
            float mo = m_s[hf][r];
            float mn = fmaxf(mo, tm);
            float rsc = __expf(mo - mn);      // 0 on first tile (mo=-inf)
            float p0 = __expf(sc0 - mn), p1 = __expf(sc1 - mn);
            float p2 = __expf(sc2 - mn), p3 = __expf(sc3 - mn);
            float ps = (p0+p1)+(p2+p3);
            ps += __shfl_xor(ps, 1); ps += __shfl_xor(ps, 2);
            ps += __shfl_xor(ps, 4); ps += __shfl_xor(ps, 8);
            if ((th & 15) == 0){ m_s[hf][r] = mn; l_s[hf][r] = l_s[hf][r]*rsc + ps; rs_s[hf][r] = rsc; }
            ushort4v pv;
            pv[0] = f2bf(p0); pv[1] = f2bf(p1); pv[2] = f2bf(p2); pv[3] = f2bf(p3);
            *(ushort4v*)&pt[hf][r][c4] = pv;
        }
        __syncthreads();
        // rescale + MFMA (wave wl of half hf: rows wl*16..+15, all 128 cols)
        int r0 = wl*16;
        #pragma unroll
        for (int reg=0;reg<4;reg++){
            float rv = rs_s[hf][r0 + ((lane>>4)<<2) + reg];
            #pragma unroll
            for (int nf=0;nf<8;nf++) acc[nf][reg] *= rv;
        }
        int arow = r0 + (lane & 15);
        int khalf = (lane >> 4) * 8;
        #pragma unroll
        for (int kk=0;kk<2;kk++){
            short8 af = *(const short8*)&pt[hf][arow][kk*32 + khalf];
            #pragma unroll
            for (int nf=0;nf<8;nf++){
                short8 bfv = *(const short8*)&vt[hf][nf*16 + (lane & 15)][kk*32 + khalf];
                acc[nf] = __builtin_amdgcn_mfma_f32_16x16x32_bf16(af, bfv, acc[nf], 0, 0, 0);
            }
        }
    }
    // merge the two halves, normalize, elu, store
    __syncthreads();
    float* mbuf = (float*)&vt[0][0][0];   // 64x128 fp32 = 32KB
    int rrb = wl*16 + ((lane>>4)<<2);
    int col = lane & 15;
    if (hf == 1){
        #pragma unroll
        for (int reg=0;reg<4;reg++){
            int r = rrb + reg;
            float m0 = m_s[0][r], m1 = m_s[1][r];
            float M = fmaxf(m0, m1);
            float e1 = __expf(m1 - M);
            #pragma unroll
            for (int nf=0;nf<8;nf++) mbuf[r*FOn + nf*16 + col] = acc[nf][reg] * e1;
        }
    }
    __syncthreads();
    if (hf == 0){
        #pragma unroll
        for (int reg=0;reg<4;reg++){
            int r = rrb + reg;
            float m0 = m_s[0][r], m1 = m_s[1][r];
            float M = fmaxf(m0, m1);
            float e0 = __expf(m0 - M), e1 = __expf(m1 - M);
            float L = l_s[0][r]*e0 + l_s[1][r]*e1;
            float inv = 1.f / L;
            #pragma unroll
            for (int nf=0;nf<8;nf++){
                float v = (acc[nf][reg]*e0 + mbuf[r*FOn + nf*16 + col]) * inv;
                v = v > 0.f ? v : (__expf(v) - 1.f);
                out[((long)(b*Nn + i0 + r))*FOn + nf*16 + col] = v;
            }
        }
    }
}

extern "C" void kernel_launch(void* const* d_in, const int* in_sizes, int n_in,
                              void* d_out, int out_size, void* d_ws, size_t ws_size,
                              hipStream_t stream){
    const float* h  = (const float*)d_in[0];
    const int* adj  = (const int*)d_in[1];
    const float* W  = (const float*)d_in[2];
    const float* a  = (const float*)d_in[3];
    float* out = (float*)d_out;
    char* ws = (char*)d_ws;
    // workspace layout (16B aligned):
    unsigned short* WT  = (unsigned short*)(ws);                   //    65,536 B (128x256 bf16)
    unsigned short* WhT = (unsigned short*)(ws + 65536);           // 4,194,304 B (8x128x2048 bf16)
    float* s1           = (float*)(ws + 65536 + 4194304);          //    65,536 B
    float* s2           = (float*)(ws + 65536 + 4194304 + 65536);  //    65,536 B

    k0_wt   <<<128, 256, 0, stream>>>(W, WT);
    k1_gemm <<<256, 256, 0, stream>>>(h, WT, a, WhT, s1, s2);
    k3_flash<<<256, 512, 0, stream>>>(adj, WhT, s1, s2, out);
}